// Round 4
// baseline (180.584 us; speedup 1.0000x reference)
//
#include <hip/hip_runtime.h>
#include <math.h>

#define NQ   512
#define NKV  1280
#define CDIM 128

// workspace layout (float offsets, 64B-aligned)
#define OFF_WDSUM  0         // 3
#define OFF_KSAT   16        // 163840 [c=128][k=1280] (transposed)
#define OFF_VSA    163856    // 163840 [k=1280][c=128]
#define OFF_KDAT   327696    // 163840
#define OFF_VDA    491536    // 163840
#define OFF_OUTSA  655376    // 65536  [n=512][c=128]
#define OFF_OUTDA  720912    // 65536
// total 786448 floats = 3.1 MB

// ---------------------------------------------------------------- kv proj
// bx<320: kv projection (4 keys); bx==320: Wdelta.sum(0).
__global__ __launch_bounds__(256) void kvproj_kernel(
    const float* __restrict__ ico,
    const float* __restrict__ wkv_sa, const float* __restrict__ wkv_da,
    const float* __restrict__ wdelta, float* __restrict__ ws)
{
  int bx = blockIdx.x, t = threadIdx.x;
  if (bx < 320) {
    __shared__ float x4[4 * CDIM];          // [j*4 + ky]
    int k0 = bx * 4;
    for (int i = t; i < 512; i += 256) {
      int ky = i >> 7, j = i & 127;
      x4[j * 4 + ky] = ico[(k0 + ky) * CDIM + j];
    }
    __syncthreads();
    const float4* wsa4 = (const float4*)(wkv_sa + t * CDIM);
    const float4* wda4 = (const float4*)(wkv_da + t * CDIM);
    float as0=0,as1=0,as2=0,as3=0, ad0=0,ad1=0,ad2=0,ad3=0;
    #pragma unroll 4
    for (int j4 = 0; j4 < 32; ++j4) {
      float4 wsv = wsa4[j4];
      float4 wdv = wda4[j4];
      float4 x0 = *(const float4*)&x4[(j4 * 4 + 0) * 4];
      float4 x1 = *(const float4*)&x4[(j4 * 4 + 1) * 4];
      float4 x2 = *(const float4*)&x4[(j4 * 4 + 2) * 4];
      float4 x3 = *(const float4*)&x4[(j4 * 4 + 3) * 4];
      as0 = fmaf(wsv.x, x0.x, as0); as1 = fmaf(wsv.x, x0.y, as1);
      as2 = fmaf(wsv.x, x0.z, as2); as3 = fmaf(wsv.x, x0.w, as3);
      ad0 = fmaf(wdv.x, x0.x, ad0); ad1 = fmaf(wdv.x, x0.y, ad1);
      ad2 = fmaf(wdv.x, x0.z, ad2); ad3 = fmaf(wdv.x, x0.w, ad3);
      as0 = fmaf(wsv.y, x1.x, as0); as1 = fmaf(wsv.y, x1.y, as1);
      as2 = fmaf(wsv.y, x1.z, as2); as3 = fmaf(wsv.y, x1.w, as3);
      ad0 = fmaf(wdv.y, x1.x, ad0); ad1 = fmaf(wdv.y, x1.y, ad1);
      ad2 = fmaf(wdv.y, x1.z, ad2); ad3 = fmaf(wdv.y, x1.w, ad3);
      as0 = fmaf(wsv.z, x2.x, as0); as1 = fmaf(wsv.z, x2.y, as1);
      as2 = fmaf(wsv.z, x2.z, as2); as3 = fmaf(wsv.z, x2.w, as3);
      ad0 = fmaf(wdv.z, x2.x, ad0); ad1 = fmaf(wdv.z, x2.y, ad1);
      ad2 = fmaf(wdv.z, x2.z, ad2); ad3 = fmaf(wdv.z, x2.w, ad3);
      as0 = fmaf(wsv.w, x3.x, as0); as1 = fmaf(wsv.w, x3.y, as1);
      as2 = fmaf(wsv.w, x3.z, as2); as3 = fmaf(wsv.w, x3.w, as3);
      ad0 = fmaf(wdv.w, x3.x, ad0); ad1 = fmaf(wdv.w, x3.y, ad1);
      ad2 = fmaf(wdv.w, x3.z, ad2); ad3 = fmaf(wdv.w, x3.w, ad3);
    }
    if (t < 128) {   // k features -> transposed [c][k]
      *(float4*)(ws + OFF_KSAT + t * NKV + k0) = make_float4(as0, as1, as2, as3);
      *(float4*)(ws + OFF_KDAT + t * NKV + k0) = make_float4(ad0, ad1, ad2, ad3);
    } else {         // v features -> [k][c]
      int c = t - 128;
      ws[OFF_VSA + (k0 + 0) * CDIM + c] = as0;
      ws[OFF_VSA + (k0 + 1) * CDIM + c] = as1;
      ws[OFF_VSA + (k0 + 2) * CDIM + c] = as2;
      ws[OFF_VSA + (k0 + 3) * CDIM + c] = as3;
      ws[OFF_VDA + (k0 + 0) * CDIM + c] = ad0;
      ws[OFF_VDA + (k0 + 1) * CDIM + c] = ad1;
      ws[OFF_VDA + (k0 + 2) * CDIM + c] = ad2;
      ws[OFF_VDA + (k0 + 3) * CDIM + c] = ad3;
    }
  } else {
    __shared__ float acc[3];
    if (t < 3) acc[t] = 0.f;
    __syncthreads();
    if (t < 128) {
      atomicAdd(&acc[0], wdelta[t * 3 + 0]);
      atomicAdd(&acc[1], wdelta[t * 3 + 1]);
      atomicAdd(&acc[2], wdelta[t * 3 + 2]);
    }
    __syncthreads();
    if (t < 3) ws[OFF_WDSUM + t] = acc[t];
  }
}

// ---------------------------------------------------------------- fused attn
// grid (256 q-pairs, 2 branches), block 256.
// phases: q-proj (fused) -> scores in regs -> softmax -> AV -> out.
__global__ __launch_bounds__(256) void attn_kernel(
    const float* __restrict__ erp, const float* __restrict__ coord,
    const float* __restrict__ wq_sa, const float* __restrict__ wq_da,
    float* __restrict__ ws)
{
  __shared__ float eq[2][CDIM];         // staged erp columns
  __shared__ float q2[CDIM * 2];        // [j*2 + r]
  __shared__ float sc[2][NKV];          // probabilities
  __shared__ float red[8];
  __shared__ float part[4][2][CDIM];
  __shared__ float qcr[2][3];
  __shared__ float wd[3];
  int t = threadIdx.x;
  int n0 = blockIdx.x * 2;
  int br = blockIdx.y;

  {  // stage the two erp columns (q rows)
    int r = t >> 7, j = t & 127;
    eq[r][j] = erp[j * NQ + n0 + r];
  }
  if (br) {
    if (t < 2) {
      int n = n0 + t;
      float x = (float)(n & 31), y = (float)(n >> 5);
      float u  = (x - 16.5f) * 0.19634954084936207f;  // pi/16
      float vv = (y -  8.5f) * 0.19634954084936207f;
      float cv = cosf(vv);
      qcr[t][0] = cv * sinf(u);
      qcr[t][1] = sinf(vv);
      qcr[t][2] = cv * cosf(u);
    }
    if (t >= 64 && t < 67) wd[t - 64] = ws[OFF_WDSUM + t - 64];
  }
  __syncthreads();

  {  // fused q projection: thread (r=t>>7, c=t&127)
    int r = t >> 7, c = t & 127;
    const float* w = br ? wq_da : wq_sa;
    const float4* w4 = (const float4*)(w + c * CDIM);
    const float4* x4 = (const float4*)eq[r];
    float a0 = 0.f, a1 = 0.f, a2 = 0.f, a3 = 0.f;
    #pragma unroll 8
    for (int j4 = 0; j4 < 32; ++j4) {
      float4 wv = w4[j4];
      float4 xv = x4[j4];
      a0 = fmaf(wv.x, xv.x, a0); a1 = fmaf(wv.y, xv.y, a1);
      a2 = fmaf(wv.z, xv.z, a2); a3 = fmaf(wv.w, xv.w, a3);
    }
    q2[c * 2 + r] = (a0 + a1) + (a2 + a3);
  }
  __syncthreads();

  // scores for k = t + 256*ki, ki<5, rows 0..1 — kept in registers
  float l0[5], l1[5];
  if (br == 0) {
    const float* K = ws + OFF_KSAT + t;
    float a0[5] = {0,0,0,0,0}, a1[5] = {0,0,0,0,0};
    #pragma unroll 4
    for (int j = 0; j < CDIM; ++j) {
      float2 q = *(const float2*)&q2[j * 2];
      const float* kj = K + j * NKV;
      #pragma unroll
      for (int ki = 0; ki < 5; ++ki) {
        float kv = kj[ki * 256];
        a0[ki] = fmaf(q.x, kv, a0[ki]);
        a1[ki] = fmaf(q.y, kv, a1[ki]);
      }
    }
    const float scale = 0.088388347648318447f;  // 128^-0.5
    #pragma unroll
    for (int ki = 0; ki < 5; ++ki) { l0[ki] = a0[ki] * scale; l1[ki] = a1[ki] * scale; }
  } else {
    const float* K = ws + OFF_KDAT + t;
    float a0[5] = {0,0,0,0,0}, a1[5] = {0,0,0,0,0};
    #pragma unroll 2
    for (int j = 0; j < CDIM; ++j) {
      float2 q = *(const float2*)&q2[j * 2];
      const float* kj = K + j * NKV;
      #pragma unroll
      for (int ki = 0; ki < 5; ++ki) {
        float kv = kj[ki * 256];
        a0[ki] += __expf(-fabsf(q.x - kv));
        a1[ki] += __expf(-fabsf(q.y - kv));
      }
    }
    float w0 = wd[0], w1 = wd[1], w2 = wd[2];
    float q00 = qcr[0][0], q01 = qcr[0][1], q02 = qcr[0][2];
    float q10 = qcr[1][0], q11 = qcr[1][1], q12 = qcr[1][2];
    #pragma unroll
    for (int ki = 0; ki < 5; ++ki) {
      int k = t + ki * 256;
      float c0 = coord[k * 3], c1 = coord[k * 3 + 1], c2 = coord[k * 3 + 2];
      float p0 = w0 * __expf(-fabsf(q00 - c0)) + w1 * __expf(-fabsf(q01 - c1))
               + w2 * __expf(-fabsf(q02 - c2));
      float p1 = w0 * __expf(-fabsf(q10 - c0)) + w1 * __expf(-fabsf(q11 - c1))
               + w2 * __expf(-fabsf(q12 - c2));
      l0[ki] = (a0[ki] + p0) * 0.0078125f;   // 1/C
      l1[ki] = (a1[ki] + p1) * 0.0078125f;
    }
  }

  // softmax (block-wide over 1280)
  float lm0 = -1e30f, lm1 = -1e30f;
  #pragma unroll
  for (int ki = 0; ki < 5; ++ki) {
    lm0 = fmaxf(lm0, l0[ki]);
    lm1 = fmaxf(lm1, l1[ki]);
  }
  for (int o = 32; o > 0; o >>= 1) {
    lm0 = fmaxf(lm0, __shfl_down(lm0, o, 64));
    lm1 = fmaxf(lm1, __shfl_down(lm1, o, 64));
  }
  if ((t & 63) == 0) { red[t >> 6] = lm0; red[4 + (t >> 6)] = lm1; }
  __syncthreads();
  float m0 = fmaxf(fmaxf(red[0], red[1]), fmaxf(red[2], red[3]));
  float m1 = fmaxf(fmaxf(red[4], red[5]), fmaxf(red[6], red[7]));
  float s0 = 0.f, s1 = 0.f;
  #pragma unroll
  for (int ki = 0; ki < 5; ++ki) {
    float e0 = __expf(l0[ki] - m0);
    float e1 = __expf(l1[ki] - m1);
    sc[0][ki * 256 + t] = e0;
    sc[1][ki * 256 + t] = e1;
    s0 += e0; s1 += e1;
  }
  for (int o = 32; o > 0; o >>= 1) {
    s0 += __shfl_down(s0, o, 64);
    s1 += __shfl_down(s1, o, 64);
  }
  __syncthreads();   // red read done by all; sc writes done
  if ((t & 63) == 0) { red[t >> 6] = s0; red[4 + (t >> 6)] = s1; }
  __syncthreads();
  float is0 = 1.0f / (red[0] + red[1] + red[2] + red[3]);
  float is1 = 1.0f / (red[4] + red[5] + red[6] + red[7]);

  // AV: 4-way k-split, float2 V loads, float4 P reads
  const float* v = ws + (br ? OFF_VDA : OFF_VSA);
  int quarter = t >> 6;
  int c0 = (t & 63) * 2;
  int kb = quarter * 320;
  float a00 = 0.f, a01 = 0.f, a10 = 0.f, a11 = 0.f;
  #pragma unroll 2
  for (int ko = 0; ko < 320; ko += 4) {
    int k = kb + ko;
    float4 p0 = *(const float4*)&sc[0][k];
    float4 p1 = *(const float4*)&sc[1][k];
    float2 va = *(const float2*)&v[(k + 0) * CDIM + c0];
    float2 vb = *(const float2*)&v[(k + 1) * CDIM + c0];
    float2 vc = *(const float2*)&v[(k + 2) * CDIM + c0];
    float2 vd = *(const float2*)&v[(k + 3) * CDIM + c0];
    a00 = fmaf(p0.x, va.x, a00); a01 = fmaf(p0.x, va.y, a01);
    a10 = fmaf(p1.x, va.x, a10); a11 = fmaf(p1.x, va.y, a11);
    a00 = fmaf(p0.y, vb.x, a00); a01 = fmaf(p0.y, vb.y, a01);
    a10 = fmaf(p1.y, vb.x, a10); a11 = fmaf(p1.y, vb.y, a11);
    a00 = fmaf(p0.z, vc.x, a00); a01 = fmaf(p0.z, vc.y, a01);
    a10 = fmaf(p1.z, vc.x, a10); a11 = fmaf(p1.z, vc.y, a11);
    a00 = fmaf(p0.w, vd.x, a00); a01 = fmaf(p0.w, vd.y, a01);
    a10 = fmaf(p1.w, vd.x, a10); a11 = fmaf(p1.w, vd.y, a11);
  }
  part[quarter][0][c0] = a00; part[quarter][0][c0 + 1] = a01;
  part[quarter][1][c0] = a10; part[quarter][1][c0 + 1] = a11;
  __syncthreads();
  {
    int r = t >> 7, c = t & 127;
    float sum = part[0][r][c] + part[1][r][c] + part[2][r][c] + part[3][r][c];
    float* o = ws + (br ? OFF_OUTDA : OFF_OUTSA);
    o[(n0 + r) * CDIM + c] = sum * (r ? is1 : is0);
  }
}

// ---------------------------------------------------------------- finalize
// one block per query row: reinterpret-transpose sa, project, gate, fuse, NCHW.
__global__ __launch_bounds__(128) void finalize_kernel(
    const float* __restrict__ psa, const float* __restrict__ bsa,
    const float* __restrict__ pda, const float* __restrict__ bda,
    const float* __restrict__ gsa, const float* __restrict__ gda,
    float* __restrict__ out, float* __restrict__ ws)
{
  __shared__ float sain[CDIM];
  __shared__ float dain[CDIM];
  __shared__ float cat[2 * CDIM];
  int i = blockIdx.x, t = threadIdx.x;
  // sa_in[i][j] = out_sa[(i%4)*128 + j][i/4]   (reference's transpose-reshape)
  sain[t] = ws[OFF_OUTSA + ((i & 3) * 128 + t) * CDIM + (i >> 2)];
  dain[t] = ws[OFF_OUTDA + i * CDIM + t];
  __syncthreads();
  const float4* p4 = (const float4*)(psa + t * CDIM);
  const float4* d4 = (const float4*)(pda + t * CDIM);
  float s0=0,s1=0,s2=0,s3=0, e0=0,e1=0,e2=0,e3=0;
  #pragma unroll 8
  for (int j4 = 0; j4 < 32; ++j4) {
    float4 wv = p4[j4];
    float4 xv = *(const float4*)&sain[j4 * 4];
    s0 = fmaf(wv.x, xv.x, s0); s1 = fmaf(wv.y, xv.y, s1);
    s2 = fmaf(wv.z, xv.z, s2); s3 = fmaf(wv.w, xv.w, s3);
    float4 wv2 = d4[j4];
    float4 yv = *(const float4*)&dain[j4 * 4];
    e0 = fmaf(wv2.x, yv.x, e0); e1 = fmaf(wv2.y, yv.y, e1);
    e2 = fmaf(wv2.z, yv.z, e2); e3 = fmaf(wv2.w, yv.w, e3);
  }
  float asa = bsa[t] + ((s0 + s1) + (s2 + s3));
  float ada = bda[t] + ((e0 + e1) + (e2 + e3));
  cat[t] = asa;
  cat[CDIM + t] = ada;
  __syncthreads();
  const float4* g14 = (const float4*)(gsa + t * 2 * CDIM);
  const float4* g24 = (const float4*)(gda + t * 2 * CDIM);
  float u0=0,u1=0,u2=0,u3=0, w0=0,w1=0,w2=0,w3=0;
  #pragma unroll 8
  for (int j4 = 0; j4 < 64; ++j4) {
    float4 gv = g14[j4];
    float4 cv = *(const float4*)&cat[j4 * 4];
    u0 = fmaf(gv.x, cv.x, u0); u1 = fmaf(gv.y, cv.y, u1);
    u2 = fmaf(gv.z, cv.z, u2); u3 = fmaf(gv.w, cv.w, u3);
    float4 gv2 = g24[j4];
    w0 = fmaf(gv2.x, cv.x, w0); w1 = fmaf(gv2.y, cv.y, w1);
    w2 = fmaf(gv2.z, cv.z, w2); w3 = fmaf(gv2.w, cv.w, w3);
  }
  float g1 = 1.0f / (1.0f + __expf(-((u0 + u1) + (u2 + u3))));
  float g2 = 1.0f / (1.0f + __expf(-((w0 + w1) + (w2 + w3))));
  out[t * NQ + i] = g1 * asa + g2 * ada;   // out[c][h][w]
}

// ---------------------------------------------------------------- launch
extern "C" void kernel_launch(void* const* d_in, const int* in_sizes, int n_in,
                              void* d_out, int out_size, void* d_ws, size_t ws_size,
                              hipStream_t stream)
{
  (void)in_sizes; (void)n_in; (void)out_size; (void)ws_size;
  const float* erp       = (const float*)d_in[0];
  const float* ico       = (const float*)d_in[1];
  const float* coord     = (const float*)d_in[2];
  const float* wq_sa     = (const float*)d_in[3];
  const float* wkv_sa    = (const float*)d_in[4];
  const float* proj_sa_w = (const float*)d_in[5];
  const float* proj_sa_b = (const float*)d_in[6];
  const float* wq_da     = (const float*)d_in[7];
  const float* wkv_da    = (const float*)d_in[8];
  const float* wdelta    = (const float*)d_in[9];
  const float* proj_da_w = (const float*)d_in[10];
  const float* proj_da_b = (const float*)d_in[11];
  const float* gate_sa   = (const float*)d_in[12];
  const float* gate_da   = (const float*)d_in[13];
  float* out = (float*)d_out;
  float* ws  = (float*)d_ws;

  hipLaunchKernelGGL(kvproj_kernel, dim3(321), dim3(256), 0, stream,
                     ico, wkv_sa, wkv_da, wdelta, ws);
  hipLaunchKernelGGL(attn_kernel, dim3(256, 2), dim3(256), 0, stream,
                     erp, coord, wq_sa, wq_da, ws);
  hipLaunchKernelGGL(finalize_kernel, dim3(512), dim3(128), 0, stream,
                     proj_sa_w, proj_sa_b, proj_da_w, proj_da_b,
                     gate_sa, gate_da, out, ws);
}